// Round 1
// baseline (459.973 us; speedup 1.0000x reference)
//
#include <hip/hip_runtime.h>
#include <cstdint>
#include <cstddef>

typedef unsigned short u16;
typedef short v8s __attribute__((ext_vector_type(8)));
typedef float v4f __attribute__((ext_vector_type(4)));
typedef unsigned short v4u16 __attribute__((ext_vector_type(4)));

#define TT 2048
#define CC 512

// ---------- scalar helpers ----------
__device__ __forceinline__ u16 f2bf(float f) {
    unsigned u = __float_as_uint(f);
    u += 0x7fffu + ((u >> 16) & 1u);   // round-to-nearest-even
    return (u16)(u >> 16);
}

__device__ __forceinline__ void gl2lds16(const void* g, void* l) {
    // async global->LDS, 16B per lane; LDS dest is wave-uniform base + lane*16
    __builtin_amdgcn_global_load_lds(
        (const __attribute__((address_space(1))) unsigned int*)g,
        (__attribute__((address_space(3))) unsigned int*)l,
        16, 0, 0);
}

// ---------- f32 -> bf16 bulk convert (weights) ----------
__global__ __launch_bounds__(256) void f2bf_k(const float* __restrict__ s,
                                              u16* __restrict__ d, int n) {
    int i = (blockIdx.x * 256 + threadIdx.x) * 4;
    if (i >= n) return;
    float4 v = *(const float4*)(s + i);
    v4u16 r;
    r[0] = f2bf(v.x); r[1] = f2bf(v.y); r[2] = f2bf(v.z); r[3] = f2bf(v.w);
    *(v4u16*)(d + i) = r;
}

// ---------- adaLN modulation: mod = silu(c) @ ada_w.T + ada_b  [8,3072] ----------
__global__ __launch_bounds__(256) void ada_kernel(const float* __restrict__ c,
                                                  const float* __restrict__ W,
                                                  const float* __restrict__ bias,
                                                  float* __restrict__ mod) {
    int idx = blockIdx.x * 4 + (threadIdx.x >> 6);   // one wave per output
    int l = threadIdx.x & 63;
    int bb = idx / 3072;
    int n = idx - bb * 3072;
    const float* cp = c + bb * CC;
    const float* wp = W + (size_t)n * CC;
    float s = 0.f;
    #pragma unroll
    for (int i = 0; i < 8; ++i) {
        int k = l * 8 + i;
        float cv = cp[k];
        float sil = cv / (1.f + __expf(-cv));
        s += sil * wp[k];
    }
    #pragma unroll
    for (int off = 32; off; off >>= 1) s += __shfl_xor(s, off, 64);
    if (l == 0) mod[idx] = s + bias[n];
}

// ---------- LN + modulate: out_bf16 = LN(x)*(1+sc) + sh, one wave per row ----------
__global__ __launch_bounds__(256) void ln_mod_kernel(const float* __restrict__ X,
                                                     const float* __restrict__ lnw,
                                                     const float* __restrict__ lnb,
                                                     const float* __restrict__ mod,
                                                     int sh_off, int sc_off,
                                                     u16* __restrict__ out) {
    int row = blockIdx.x * 4 + (threadIdx.x >> 6);
    int l = threadIdx.x & 63;
    int b = row >> 11;   // row / 2048
    const float* xr = X + (size_t)row * CC + l * 8;
    float4 va = *(const float4*)(xr);
    float4 vb = *(const float4*)(xr + 4);
    float v[8] = {va.x, va.y, va.z, va.w, vb.x, vb.y, vb.z, vb.w};
    float s = 0.f;
    #pragma unroll
    for (int i = 0; i < 8; ++i) s += v[i];
    #pragma unroll
    for (int off = 32; off; off >>= 1) s += __shfl_xor(s, off, 64);
    float mean = s * (1.f / CC);
    float q = 0.f;
    #pragma unroll
    for (int i = 0; i < 8; ++i) { float d = v[i] - mean; q += d * d; }
    #pragma unroll
    for (int off = 32; off; off >>= 1) q += __shfl_xor(q, off, 64);
    float rstd = rsqrtf(q * (1.f / CC) + 1e-5f);
    int col = l * 8;
    const float* shp = mod + b * 3072 + sh_off + col;
    const float* scp = mod + b * 3072 + sc_off + col;
    v8s st;
    #pragma unroll
    for (int i = 0; i < 8; ++i) {
        float hv = (v[i] - mean) * rstd * lnw[col + i] + lnb[col + i];
        float r = hv * (1.f + scp[i]) + shp[i];
        st[i] = (short)f2bf(r);
    }
    *(v8s*)(out + (size_t)row * CC + col) = st;
}

// ---------- tiled bf16 MFMA GEMM: C[M,N] = A[M,K] @ W[N,K]^T + bias ----------
// MODE 0: out = bf16(acc+bias)
// MODE 1: out = bf16(gelu_tanh(acc+bias))
// MODE 2: out_f32 = resid + gate[b,col]*(acc+bias)   (N==512, gate stride 3072)
template <int MODE>
__global__ __launch_bounds__(256)
void gemm_bt(const u16* __restrict__ A, const u16* __restrict__ W,
             const float* __restrict__ bias, void* __restrict__ outp,
             const float* __restrict__ resid, const float* __restrict__ gate,
             int M, int N, int K) {
    __shared__ alignas(16) u16 Al[2][4096];   // [128][32] swizzled
    __shared__ alignas(16) u16 Bl[2][4096];
    const int bn = blockIdx.x << 7, bm = blockIdx.y << 7;
    const int tid = threadIdx.x;
    const int w = tid >> 6, l = tid & 63;
    const int hi = l >> 4, lo = l & 15;
    const int wr = (w >> 1) << 6, wc = (w & 1) << 6;

    v4f acc[4][4] = {};

    const int srow = l >> 2;   // row within 16-row chunk
    const int sp = l & 3;      // physical 16B slot within 64B row

    const int NT = K >> 5;

    auto stage = [&](int buf, int kt) {
        const int k0 = kt << 5;
        #pragma unroll
        for (int i = 0; i < 2; ++i) {
            const int c = w + (i << 2);            // 1KB chunk id, wave-uniform
            const int row = (c << 4) + srow;
            const int lg = sp ^ ((row >> 1) & 3);  // logical k-chunk for this slot
            gl2lds16(A + (size_t)(bm + row) * K + k0 + (lg << 3), &Al[buf][c << 9]);
            gl2lds16(W + (size_t)(bn + row) * K + k0 + (lg << 3), &Bl[buf][c << 9]);
        }
    };

    stage(0, 0);
    __syncthreads();
    int cur = 0;
    for (int t = 0; t < NT; ++t) {
        if (t + 1 < NT) stage(cur ^ 1, t + 1);
        const u16* Ab = Al[cur];
        const u16* Bb = Bl[cur];
        v8s aF[4], bF[4];
        #pragma unroll
        for (int mi = 0; mi < 4; ++mi) {
            int r = wr + (mi << 4) + lo;
            aF[mi] = *(const v8s*)(Ab + (r << 5) + ((hi ^ ((r >> 1) & 3)) << 3));
        }
        #pragma unroll
        for (int ni = 0; ni < 4; ++ni) {
            int r = wc + (ni << 4) + lo;
            bF[ni] = *(const v8s*)(Bb + (r << 5) + ((hi ^ ((r >> 1) & 3)) << 3));
        }
        #pragma unroll
        for (int mi = 0; mi < 4; ++mi)
            #pragma unroll
            for (int ni = 0; ni < 4; ++ni)
                acc[mi][ni] = __builtin_amdgcn_mfma_f32_16x16x32_bf16(
                    aF[mi], bF[ni], acc[mi][ni], 0, 0, 0);
        __syncthreads();
        cur ^= 1;
    }

    // epilogue: C/D layout row = 4*hi + j, col = lo (within each 16x16 frag)
    #pragma unroll
    for (int mi = 0; mi < 4; ++mi) {
        #pragma unroll
        for (int ni = 0; ni < 4; ++ni) {
            int col = bn + wc + (ni << 4) + lo;
            float bv = bias[col];
            #pragma unroll
            for (int j = 0; j < 4; ++j) {
                int row = bm + wr + (mi << 4) + hi * 4 + j;
                float v = acc[mi][ni][j] + bv;
                if constexpr (MODE == 0) {
                    ((u16*)outp)[(size_t)row * N + col] = f2bf(v);
                } else if constexpr (MODE == 1) {
                    float g = 0.5f * v * (1.f + tanhf(0.7978845608028654f *
                                                      (v + 0.044715f * v * v * v)));
                    ((u16*)outp)[(size_t)row * N + col] = f2bf(g);
                } else {
                    float r = resid[(size_t)row * N + col];
                    float gt = gate[(row >> 11) * 3072 + col];
                    ((float*)outp)[(size_t)row * N + col] = r + gt * v;
                }
            }
        }
    }
}

// ---------- flash attention fwd: qkv bf16 [B,T,1536] -> O bf16 [B,T,512] ----------
__global__ __launch_bounds__(256)
void attn_kernel(const u16* __restrict__ qkv, u16* __restrict__ O) {
    __shared__ alignas(16) u16 Kl[64 * 64];        // row-major, chunk-XOR swizzled
    __shared__ alignas(16) u16 Vt[64 * 72];        // V^T [dh][kv], padded rows
    __shared__ alignas(16) u16 Pl[4][16 * 72];     // per-wave P tile, padded rows
    const int bh = blockIdx.y;
    const int b = bh >> 3, h = bh & 7;
    const int qt = blockIdx.x;
    const int tid = threadIdx.x, w = tid >> 6, l = tid & 63;
    const int hi = l >> 4, lo = l & 15;

    // Q fragments (A operand): m = lo, k = 32*kh + hi*8 + j ; pre-held in regs
    const int qrow = qt * 64 + w * 16 + lo;
    const u16* qb = qkv + ((size_t)(b * TT + qrow) * 1536 + h * 64);
    v8s qf0 = *(const v8s*)(qb + hi * 8);
    v8s qf1 = *(const v8s*)(qb + 32 + hi * 8);

    v4f o[4] = {};
    float mrow[4] = {-1e30f, -1e30f, -1e30f, -1e30f};
    float lrow[4] = {0.f, 0.f, 0.f, 0.f};

    // V staging assignment: 4 lanes share a row-pair (64B coalesced reads)
    const int vp = (w * 16 + (l >> 2)) & 31;        // kv row-pair 0..31
    const int vch = (l & 3) + ((w >> 1) << 2);      // dh 8-chunk 0..7

    const int r8 = l >> 3;
    const int kc = (l & 7) ^ r8;                    // logical k-chunk for K staging

    for (int kt = 0; kt < 32; ++kt) {
        __syncthreads();   // previous iteration's reads complete
        // --- stage K tile via global_load_lds (swizzled) ---
        #pragma unroll
        for (int i = 0; i < 2; ++i) {
            int cc = w + (i << 2);                  // 1KB chunk (8 rows)
            int row = (cc << 3) + r8;
            gl2lds16(qkv + ((size_t)(b * TT + kt * 64 + row) * 1536 + 512 + h * 64 + kc * 8),
                     &Kl[cc << 9]);
        }
        // --- stage V transposed (reg path, paired ds_write_b32) ---
        {
            int r0 = 2 * vp;
            const u16* v0 = qkv + ((size_t)(b * TT + kt * 64 + r0) * 1536 + 1024 + h * 64 + vch * 8);
            v8s a = *(const v8s*)v0;
            v8s bb2 = *(const v8s*)(v0 + 1536);
            #pragma unroll
            for (int e = 0; e < 8; ++e) {
                unsigned pk = (unsigned)(u16)a[e] | ((unsigned)(u16)bb2[e] << 16);
                *(unsigned*)(&Vt[(vch * 8 + e) * 72 + r0]) = pk;
            }
        }
        __syncthreads();

        // --- S = Q K^T (per wave: 16 q-rows x 64 kv) ---
        v4f s[4];
        #pragma unroll
        for (int nt = 0; nt < 4; ++nt) {
            int r = nt * 16 + lo;                   // kv row (B operand n-index)
            int swz = r & 7;
            v8s k0 = *(const v8s*)(Kl + (r << 6) + (((hi) ^ swz) << 3));
            v8s k1 = *(const v8s*)(Kl + (r << 6) + (((hi + 4) ^ swz) << 3));
            v4f z = {};
            z = __builtin_amdgcn_mfma_f32_16x16x32_bf16(qf0, k0, z, 0, 0, 0);
            s[nt] = __builtin_amdgcn_mfma_f32_16x16x32_bf16(qf1, k1, z, 0, 0, 0);
        }
        #pragma unroll
        for (int nt = 0; nt < 4; ++nt) s[nt] *= 0.125f;   // 1/sqrt(64)

        // --- online softmax (rows live in lanes sharing hi; 16-lane reduce) ---
        #pragma unroll
        for (int j = 0; j < 4; ++j) {
            float vm = fmaxf(fmaxf(s[0][j], s[1][j]), fmaxf(s[2][j], s[3][j]));
            #pragma unroll
            for (int off = 1; off < 16; off <<= 1) vm = fmaxf(vm, __shfl_xor(vm, off, 64));
            float mnew = fmaxf(mrow[j], vm);
            float alpha = __expf(mrow[j] - mnew);
            mrow[j] = mnew;
            float rs = 0.f;
            #pragma unroll
            for (int nt = 0; nt < 4; ++nt) {
                float pv = __expf(s[nt][j] - mnew);
                s[nt][j] = pv;
                rs += pv;
            }
            #pragma unroll
            for (int off = 1; off < 16; off <<= 1) rs += __shfl_xor(rs, off, 64);
            lrow[j] = lrow[j] * alpha + rs;
            #pragma unroll
            for (int dt = 0; dt < 4; ++dt) o[dt][j] *= alpha;
        }

        // --- P -> LDS (wave-local), then PV MFMA ---
        u16* Pw = &Pl[w][0];
        #pragma unroll
        for (int nt = 0; nt < 4; ++nt)
            #pragma unroll
            for (int j = 0; j < 4; ++j)
                Pw[(hi * 4 + j) * 72 + nt * 16 + lo] = f2bf(s[nt][j]);

        v8s pf0 = *(const v8s*)(Pw + lo * 72 + hi * 8);
        v8s pf1 = *(const v8s*)(Pw + lo * 72 + 32 + hi * 8);
        #pragma unroll
        for (int dt = 0; dt < 4; ++dt) {
            const u16* vb2 = Vt + (dt * 16 + lo) * 72;
            v8s vf0 = *(const v8s*)(vb2 + hi * 8);
            v8s vf1 = *(const v8s*)(vb2 + 32 + hi * 8);
            o[dt] = __builtin_amdgcn_mfma_f32_16x16x32_bf16(pf0, vf0, o[dt], 0, 0, 0);
            o[dt] = __builtin_amdgcn_mfma_f32_16x16x32_bf16(pf1, vf1, o[dt], 0, 0, 0);
        }
    }

    // --- write O (normalize by l) ---
    #pragma unroll
    for (int j = 0; j < 4; ++j) {
        float inv = 1.f / lrow[j];
        int row = qt * 64 + w * 16 + hi * 4 + j;
        u16* ob = O + ((size_t)(b * TT + row) * 512 + h * 64);
        #pragma unroll
        for (int dt = 0; dt < 4; ++dt)
            ob[dt * 16 + lo] = f2bf(o[dt][j] * inv);
    }
}

// ---------- launcher ----------
extern "C" void kernel_launch(void* const* d_in, const int* in_sizes, int n_in,
                              void* d_out, int out_size, void* d_ws, size_t ws_size,
                              hipStream_t stream) {
    const float* x = (const float*)d_in[0];
    const float* c = (const float*)d_in[1];
    const float* qkv_w = (const float*)d_in[2];
    const float* qkv_b = (const float*)d_in[3];
    const float* proj_w = (const float*)d_in[4];
    const float* proj_b = (const float*)d_in[5];
    const float* ada_w = (const float*)d_in[6];
    const float* ada_b = (const float*)d_in[7];
    const float* fc1_w = (const float*)d_in[8];
    const float* fc1_b = (const float*)d_in[9];
    const float* fc2_w = (const float*)d_in[10];
    const float* fc2_b = (const float*)d_in[11];
    const float* ln1_w = (const float*)d_in[12];
    const float* ln1_b = (const float*)d_in[13];
    const float* ln2_w = (const float*)d_in[14];
    const float* ln2_b = (const float*)d_in[15];

    char* p = (char*)d_ws;
    auto carve = [&](size_t bytes) -> char* {
        char* r = p;
        p += (bytes + 255) & ~(size_t)255;
        return r;
    };
    float* mod  = (float*)carve((size_t)8 * 3072 * 4);
    u16* hbuf   = (u16*)carve((size_t)16384 * 512 * 2);    // ln1 out, reused for ln2 out
    u16* qkvb   = (u16*)carve((size_t)16384 * 1536 * 2);
    u16* attno  = (u16*)carve((size_t)16384 * 512 * 2);
    float* x1   = (float*)carve((size_t)16384 * 512 * 4);
    u16* wq     = (u16*)carve((size_t)1536 * 512 * 2);
    u16* wpj    = (u16*)carve((size_t)512 * 512 * 2);
    u16* w1     = (u16*)carve((size_t)2048 * 512 * 2);
    u16* w2     = (u16*)carve((size_t)512 * 2048 * 2);
    u16* fc1g   = qkvb;   // alias: fc1 output [16384,2048] over qkv+attno (both dead)

    // weights -> bf16
    f2bf_k<<<(1536 * 512) / 1024, 256, 0, stream>>>(qkv_w, wq, 1536 * 512);
    f2bf_k<<<(512 * 512) / 1024, 256, 0, stream>>>(proj_w, wpj, 512 * 512);
    f2bf_k<<<(2048 * 512) / 1024, 256, 0, stream>>>(fc1_w, w1, 2048 * 512);
    f2bf_k<<<(512 * 2048) / 1024, 256, 0, stream>>>(fc2_w, w2, 512 * 2048);

    // modulation
    ada_kernel<<<24576 / 4, 256, 0, stream>>>(c, ada_w, ada_b, mod);

    // attention branch
    ln_mod_kernel<<<16384 / 4, 256, 0, stream>>>(x, ln1_w, ln1_b, mod, 0, 512, hbuf);
    gemm_bt<0><<<dim3(12, 128), 256, 0, stream>>>(hbuf, wq, qkv_b, qkvb,
                                                  nullptr, nullptr, 16384, 1536, 512);
    attn_kernel<<<dim3(32, 64), 256, 0, stream>>>(qkvb, attno);
    gemm_bt<2><<<dim3(4, 128), 256, 0, stream>>>(attno, wpj, proj_b, x1,
                                                 x, mod + 2 * 512, 16384, 512, 512);

    // MLP branch
    ln_mod_kernel<<<16384 / 4, 256, 0, stream>>>(x1, ln2_w, ln2_b, mod, 3 * 512, 4 * 512, hbuf);
    gemm_bt<1><<<dim3(16, 128), 256, 0, stream>>>(hbuf, w1, fc1_b, fc1g,
                                                  nullptr, nullptr, 16384, 2048, 512);
    gemm_bt<2><<<dim3(4, 128), 256, 0, stream>>>(fc1g, w2, fc2_b, (float*)d_out,
                                                 x1, mod + 5 * 512, 16384, 512, 2048);
}

// Round 2
// 320.986 us; speedup vs baseline: 1.4330x; 1.4330x over previous
//
#include <hip/hip_runtime.h>
#include <cstdint>
#include <cstddef>

typedef unsigned short u16;
typedef short v8s __attribute__((ext_vector_type(8)));
typedef short v4s __attribute__((ext_vector_type(4)));
typedef float v4f __attribute__((ext_vector_type(4)));
typedef float f32x16 __attribute__((ext_vector_type(16)));
typedef unsigned int v4u __attribute__((ext_vector_type(4)));
typedef unsigned short v4u16 __attribute__((ext_vector_type(4)));

#define TT 2048
#define CC 512

// ---------- scalar helpers ----------
__device__ __forceinline__ u16 f2bf(float f) {
    unsigned u = __float_as_uint(f);
    u += 0x7fffu + ((u >> 16) & 1u);   // round-to-nearest-even
    return (u16)(u >> 16);
}

__device__ __forceinline__ unsigned cvt_pk_bf16(float lo, float hi) {
    unsigned r;
    asm("v_cvt_pk_bf16_f32 %0, %1, %2" : "=v"(r) : "v"(lo), "v"(hi));
    return r;
}

// swap: x = [a_lo, b_lo], y = [a_hi, b_hi]  (exchanges a's hi half with b's lo half)
__device__ __forceinline__ void swap32(unsigned a, unsigned b, unsigned& x, unsigned& y) {
#if __has_builtin(__builtin_amdgcn_permlane32_swap)
    auto r = __builtin_amdgcn_permlane32_swap(a, b, false, false);
    x = r[0]; y = r[1];
#else
    unsigned bx = (unsigned)__shfl_xor((int)b, 32, 64);
    unsigned ax = (unsigned)__shfl_xor((int)a, 32, 64);
    bool hi5 = (threadIdx.x & 32) != 0;
    x = hi5 ? bx : a;
    y = hi5 ? b : ax;
#endif
}

__device__ __forceinline__ void gl2lds16(const void* g, void* l) {
    __builtin_amdgcn_global_load_lds(
        (const __attribute__((address_space(1))) unsigned int*)g,
        (__attribute__((address_space(3))) unsigned int*)l,
        16, 0, 0);
}

// ---------- f32 -> bf16 bulk convert (weights) ----------
__global__ __launch_bounds__(256) void f2bf_k(const float* __restrict__ s,
                                              u16* __restrict__ d, int n) {
    int i = (blockIdx.x * 256 + threadIdx.x) * 4;
    if (i >= n) return;
    float4 v = *(const float4*)(s + i);
    v4u16 r;
    r[0] = f2bf(v.x); r[1] = f2bf(v.y); r[2] = f2bf(v.z); r[3] = f2bf(v.w);
    *(v4u16*)(d + i) = r;
}

// ---------- adaLN modulation ----------
__global__ __launch_bounds__(256) void ada_kernel(const float* __restrict__ c,
                                                  const float* __restrict__ W,
                                                  const float* __restrict__ bias,
                                                  float* __restrict__ mod) {
    int idx = blockIdx.x * 4 + (threadIdx.x >> 6);
    int l = threadIdx.x & 63;
    int bb = idx / 3072;
    int n = idx - bb * 3072;
    const float* cp = c + bb * CC;
    const float* wp = W + (size_t)n * CC;
    float s = 0.f;
    #pragma unroll
    for (int i = 0; i < 8; ++i) {
        int k = l * 8 + i;
        float cv = cp[k];
        float sil = cv / (1.f + __expf(-cv));
        s += sil * wp[k];
    }
    #pragma unroll
    for (int off = 32; off; off >>= 1) s += __shfl_xor(s, off, 64);
    if (l == 0) mod[idx] = s + bias[n];
}

// ---------- LN + modulate ----------
__global__ __launch_bounds__(256) void ln_mod_kernel(const float* __restrict__ X,
                                                     const float* __restrict__ lnw,
                                                     const float* __restrict__ lnb,
                                                     const float* __restrict__ mod,
                                                     int sh_off, int sc_off,
                                                     u16* __restrict__ out) {
    int row = blockIdx.x * 4 + (threadIdx.x >> 6);
    int l = threadIdx.x & 63;
    int b = row >> 11;
    const float* xr = X + (size_t)row * CC + l * 8;
    float4 va = *(const float4*)(xr);
    float4 vb = *(const float4*)(xr + 4);
    float v[8] = {va.x, va.y, va.z, va.w, vb.x, vb.y, vb.z, vb.w};
    float s = 0.f;
    #pragma unroll
    for (int i = 0; i < 8; ++i) s += v[i];
    #pragma unroll
    for (int off = 32; off; off >>= 1) s += __shfl_xor(s, off, 64);
    float mean = s * (1.f / CC);
    float q = 0.f;
    #pragma unroll
    for (int i = 0; i < 8; ++i) { float d = v[i] - mean; q += d * d; }
    #pragma unroll
    for (int off = 32; off; off >>= 1) q += __shfl_xor(q, off, 64);
    float rstd = rsqrtf(q * (1.f / CC) + 1e-5f);
    int col = l * 8;
    const float* shp = mod + b * 3072 + sh_off + col;
    const float* scp = mod + b * 3072 + sc_off + col;
    v8s st;
    #pragma unroll
    for (int i = 0; i < 8; ++i) {
        float hv = (v[i] - mean) * rstd * lnw[col + i] + lnb[col + i];
        float r = hv * (1.f + scp[i]) + shp[i];
        st[i] = (short)f2bf(r);
    }
    *(v8s*)(out + (size_t)row * CC + col) = st;
}

// ---------- tiled bf16 MFMA GEMM ----------
template <int MODE>
__global__ __launch_bounds__(256)
void gemm_bt(const u16* __restrict__ A, const u16* __restrict__ W,
             const float* __restrict__ bias, void* __restrict__ outp,
             const float* __restrict__ resid, const float* __restrict__ gate,
             int M, int N, int K) {
    __shared__ alignas(16) u16 Al[2][4096];
    __shared__ alignas(16) u16 Bl[2][4096];
    const int bn = blockIdx.x << 7, bm = blockIdx.y << 7;
    const int tid = threadIdx.x;
    const int w = tid >> 6, l = tid & 63;
    const int hi = l >> 4, lo = l & 15;
    const int wr = (w >> 1) << 6, wc = (w & 1) << 6;

    v4f acc[4][4] = {};

    const int srow = l >> 2;
    const int sp = l & 3;
    const int NT = K >> 5;

    auto stage = [&](int buf, int kt) {
        const int k0 = kt << 5;
        #pragma unroll
        for (int i = 0; i < 2; ++i) {
            const int c = w + (i << 2);
            const int row = (c << 4) + srow;
            const int lg = sp ^ ((row >> 1) & 3);
            gl2lds16(A + (size_t)(bm + row) * K + k0 + (lg << 3), &Al[buf][c << 9]);
            gl2lds16(W + (size_t)(bn + row) * K + k0 + (lg << 3), &Bl[buf][c << 9]);
        }
    };

    stage(0, 0);
    __syncthreads();
    int cur = 0;
    for (int t = 0; t < NT; ++t) {
        if (t + 1 < NT) stage(cur ^ 1, t + 1);
        const u16* Ab = Al[cur];
        const u16* Bb = Bl[cur];
        v8s aF[4], bF[4];
        #pragma unroll
        for (int mi = 0; mi < 4; ++mi) {
            int r = wr + (mi << 4) + lo;
            aF[mi] = *(const v8s*)(Ab + (r << 5) + ((hi ^ ((r >> 1) & 3)) << 3));
        }
        #pragma unroll
        for (int ni = 0; ni < 4; ++ni) {
            int r = wc + (ni << 4) + lo;
            bF[ni] = *(const v8s*)(Bb + (r << 5) + ((hi ^ ((r >> 1) & 3)) << 3));
        }
        #pragma unroll
        for (int mi = 0; mi < 4; ++mi)
            #pragma unroll
            for (int ni = 0; ni < 4; ++ni)
                acc[mi][ni] = __builtin_amdgcn_mfma_f32_16x16x32_bf16(
                    aF[mi], bF[ni], acc[mi][ni], 0, 0, 0);
        __syncthreads();
        cur ^= 1;
    }

    #pragma unroll
    for (int mi = 0; mi < 4; ++mi) {
        #pragma unroll
        for (int ni = 0; ni < 4; ++ni) {
            int col = bn + wc + (ni << 4) + lo;
            float bv = bias[col];
            #pragma unroll
            for (int j = 0; j < 4; ++j) {
                int row = bm + wr + (mi << 4) + hi * 4 + j;
                float v = acc[mi][ni][j] + bv;
                if constexpr (MODE == 0) {
                    ((u16*)outp)[(size_t)row * N + col] = f2bf(v);
                } else if constexpr (MODE == 1) {
                    float u2 = 1.5957691216057308f * (v + 0.044715f * v * v * v);
                    float g = v / (1.f + __expf(-u2));   // == 0.5v(1+tanh(u))
                    ((u16*)outp)[(size_t)row * N + col] = f2bf(g);
                } else {
                    float r = resid[(size_t)row * N + col];
                    float gt = gate[(row >> 11) * 3072 + col];
                    ((float*)outp)[(size_t)row * N + col] = r + gt * v;
                }
            }
        }
    }
}

// ---------- flash attention, 8-wave 32x32 swapped structure ----------
// qkv bf16 [B*T,1536] -> O bf16 [B*T,512]
// Block: 512 thr (8 waves), covers 256 q rows of one (b,h). Wave: 32 q rows.
// S^T = mfma32x32x16(K, Q)  (q lane-local), softmax in-register,
// P -> bf16 via cvt_pk + permlane32_swap, O^T = mfma(V^T, P).
__global__ __launch_bounds__(512, 1)
void attn_kernel(const u16* __restrict__ qkv, u16* __restrict__ O) {
    __shared__ alignas(16) u16 smem[18432];          // 36 KB
    const int tid = threadIdx.x;
    const int w = tid >> 6, l = tid & 63;
    const int l31 = l & 31, l5 = l >> 5;
    const int bh = blockIdx.y, b = bh >> 3, h = bh & 7;
    const int qt = blockIdx.x;
    const float SC = 0.125f;                          // 1/sqrt(64)

    // --- Q fragments (B operand): n=q=l31, k = ks*16 + l5*8 + j ---
    const int qrow = qt * 256 + w * 32 + l31;
    const u16* qp = qkv + (size_t)(b * TT + qrow) * 1536 + h * 64;
    v8s qf[4];
    #pragma unroll
    for (int ks = 0; ks < 4; ++ks) qf[ks] = *(const v8s*)(qp + ks * 16 + l5 * 8);

    // --- staging helpers ---
    const int krow = (w << 3) + (l >> 3);             // K stage row (0..63)
    const int kc = (l & 7) ^ (l >> 3);                // logical k-chunk (inverse swizzle)
    const int vp = tid >> 4;                          // kv pair 0..31
    const int c4 = (tid & 15) << 2;                   // dh chunk base 0,4,..,60

    auto stageK = [&](int kt, int buf) {
        gl2lds16(qkv + (size_t)(b * TT + kt * 64 + krow) * 1536 + 512 + h * 64 + kc * 8,
                 smem + buf * 4096 + (w << 9));
    };
    v4s va, vb;
    auto loadV = [&](int kt) {
        const u16* vs = qkv + (size_t)(b * TT + kt * 64 + 2 * vp) * 1536 + 1024 + h * 64 + c4;
        va = *(const v4s*)vs;
        vb = *(const v4s*)(vs + 1536);
    };
    auto writeV = [&](int buf) {
        char* Vb = (char*)(smem + 8192 + buf * 4096);
        #pragma unroll
        for (int e = 0; e < 4; ++e) {
            int d = c4 + e;
            unsigned pk = (unsigned)(u16)va[e] | ((unsigned)(u16)vb[e] << 16);
            *(unsigned*)(Vb + ((d << 7) | ((vp << 2) ^ ((d & 7) << 4)))) = pk;
        }
    };
    // A-operand frag read (row = t*32 + l31, 16B slot logical 2ks+l5, XOR row&7)
    const int physbase = l31 & 7;
    auto afrag = [&](const char* base, int t, int ks) -> v8s {
        int row = t * 32 + l31;
        int phys = ((ks << 1) + l5) ^ physbase;
        return *(const v8s*)(base + (row << 7) + (phys << 4));
    };

    // --- prologue ---
    stageK(0, 0);
    loadV(0);
    writeV(0);
    __syncthreads();

    f32x16 st[2];
    f32x16 o[2] = {};
    float mrun = -1e30f, lrun = 0.f;
    int cur = 0;

    for (int kt = 0; kt < 32; ++kt) {
        if (kt + 1 < 32) { stageK(kt + 1, cur ^ 1); loadV(kt + 1); }
        const char* Kb = (const char*)(smem + cur * 4096);
        const char* Vb = (const char*)(smem + 8192 + cur * 4096);

        // --- S^T = K * Q^T ---
        st[0] = (f32x16)0.f; st[1] = (f32x16)0.f;
        __builtin_amdgcn_s_setprio(1);
        #pragma unroll
        for (int ks = 0; ks < 4; ++ks) {
            v8s k0 = afrag(Kb, 0, ks);
            v8s k1 = afrag(Kb, 1, ks);
            st[0] = __builtin_amdgcn_mfma_f32_32x32x16_bf16(k0, qf[ks], st[0], 0, 0, 0);
            st[1] = __builtin_amdgcn_mfma_f32_32x32x16_bf16(k1, qf[ks], st[1], 0, 0, 0);
        }
        __builtin_amdgcn_s_setprio(0);

        // --- online softmax (q = l31; this lane holds 32 of 64 kv, partner l^32 rest) ---
        float tmax = st[0][0];
        #pragma unroll
        for (int r = 1; r < 16; ++r) tmax = fmaxf(tmax, st[0][r]);
        #pragma unroll
        for (int r = 0; r < 16; ++r) tmax = fmaxf(tmax, st[1][r]);
        tmax = fmaxf(tmax, __shfl_xor(tmax, 32, 64));
        float mnew = fmaxf(mrun, tmax);
        float alpha = __expf((mrun - mnew) * SC);
        float rsum = 0.f;
        #pragma unroll
        for (int t2 = 0; t2 < 2; ++t2)
            #pragma unroll
            for (int r = 0; r < 16; ++r) {
                float p = __expf((st[t2][r] - mnew) * SC);
                st[t2][r] = p;
                rsum += p;
            }
        rsum += __shfl_xor(rsum, 32, 64);
        lrun = lrun * alpha + rsum;
        mrun = mnew;
        #pragma unroll
        for (int t2 = 0; t2 < 2; ++t2)
            #pragma unroll
            for (int r = 0; r < 16; ++r) o[t2][r] *= alpha;

        // --- P pack (cvt_pk + permlane32_swap) and O^T += V^T * P ---
        __builtin_amdgcn_s_setprio(1);
        #pragma unroll
        for (int ks = 0; ks < 4; ++ks) {
            const int tt = ks >> 1, rb = (ks & 1) * 8;
            unsigned pkA = cvt_pk_bf16(st[tt][rb + 0], st[tt][rb + 1]);
            unsigned pkB = cvt_pk_bf16(st[tt][rb + 4], st[tt][rb + 5]);
            unsigned pkC = cvt_pk_bf16(st[tt][rb + 2], st[tt][rb + 3]);
            unsigned pkD = cvt_pk_bf16(st[tt][rb + 6], st[tt][rb + 7]);
            unsigned w0, w1, w2, w3;
            swap32(pkA, pkB, w0, w2);
            swap32(pkC, pkD, w1, w3);
            v4u pw; pw[0] = w0; pw[1] = w1; pw[2] = w2; pw[3] = w3;
            v8s pa = __builtin_bit_cast(v8s, pw);
            v8s vf0 = afrag(Vb, 0, ks);
            v8s vf1 = afrag(Vb, 1, ks);
            o[0] = __builtin_amdgcn_mfma_f32_32x32x16_bf16(vf0, pa, o[0], 0, 0, 0);
            o[1] = __builtin_amdgcn_mfma_f32_32x32x16_bf16(vf1, pa, o[1], 0, 0, 0);
        }
        __builtin_amdgcn_s_setprio(0);

        if (kt + 1 < 32) writeV(cur ^ 1);
        __syncthreads();
        cur ^= 1;
    }

    // --- epilogue: normalize, transpose via LDS, coalesced store ---
    float inv = 1.f / lrun;
    char* outw = (char*)smem + w * 4608;              // 32 q rows x 72 u16
    #pragma unroll
    for (int t2 = 0; t2 < 2; ++t2)
        #pragma unroll
        for (int r = 0; r < 16; r += 2) {
            int dh = t2 * 32 + (r & 3) + ((r >> 2) << 3) + (l5 << 2);
            unsigned pk = cvt_pk_bf16(o[t2][r] * inv, o[t2][r + 1] * inv);
            *(unsigned*)(outw + l31 * 144 + dh * 2) = pk;
        }
    __syncthreads();
    #pragma unroll
    for (int i = 0; i < 4; ++i) {
        int idx = (i << 9) + tid;
        int qq = idx >> 3, cch = idx & 7;
        v8s vd = *(const v8s*)((char*)smem + (qq >> 5) * 4608 + (qq & 31) * 144 + cch * 16);
        *(v8s*)(O + (size_t)(b * TT + qt * 256 + qq) * 512 + h * 64 + cch * 8) = vd;
    }
}

// ---------- launcher ----------
extern "C" void kernel_launch(void* const* d_in, const int* in_sizes, int n_in,
                              void* d_out, int out_size, void* d_ws, size_t ws_size,
                              hipStream_t stream) {
    const float* x = (const float*)d_in[0];
    const float* c = (const float*)d_in[1];
    const float* qkv_w = (const float*)d_in[2];
    const float* qkv_b = (const float*)d_in[3];
    const float* proj_w = (const float*)d_in[4];
    const float* proj_b = (const float*)d_in[5];
    const float* ada_w = (const float*)d_in[6];
    const float* ada_b = (const float*)d_in[7];
    const float* fc1_w = (const float*)d_in[8];
    const float* fc1_b = (const float*)d_in[9];
    const float* fc2_w = (const float*)d_in[10];
    const float* fc2_b = (const float*)d_in[11];
    const float* ln1_w = (const float*)d_in[12];
    const float* ln1_b = (const float*)d_in[13];
    const float* ln2_w = (const float*)d_in[14];
    const float* ln2_b = (const float*)d_in[15];

    char* p = (char*)d_ws;
    auto carve = [&](size_t bytes) -> char* {
        char* r = p;
        p += (bytes + 255) & ~(size_t)255;
        return r;
    };
    float* mod  = (float*)carve((size_t)8 * 3072 * 4);
    u16* hbuf   = (u16*)carve((size_t)16384 * 512 * 2);
    u16* qkvb   = (u16*)carve((size_t)16384 * 1536 * 2);
    u16* attno  = (u16*)carve((size_t)16384 * 512 * 2);
    float* x1   = (float*)carve((size_t)16384 * 512 * 4);
    u16* wq     = (u16*)carve((size_t)1536 * 512 * 2);
    u16* wpj    = (u16*)carve((size_t)512 * 512 * 2);
    u16* w1     = (u16*)carve((size_t)2048 * 512 * 2);
    u16* w2     = (u16*)carve((size_t)512 * 2048 * 2);
    u16* fc1g   = qkvb;   // alias fc1 output over qkv (dead after attn)

    f2bf_k<<<(1536 * 512) / 1024, 256, 0, stream>>>(qkv_w, wq, 1536 * 512);
    f2bf_k<<<(512 * 512) / 1024, 256, 0, stream>>>(proj_w, wpj, 512 * 512);
    f2bf_k<<<(2048 * 512) / 1024, 256, 0, stream>>>(fc1_w, w1, 2048 * 512);
    f2bf_k<<<(512 * 2048) / 1024, 256, 0, stream>>>(fc2_w, w2, 512 * 2048);

    ada_kernel<<<24576 / 4, 256, 0, stream>>>(c, ada_w, ada_b, mod);

    ln_mod_kernel<<<16384 / 4, 256, 0, stream>>>(x, ln1_w, ln1_b, mod, 0, 512, hbuf);
    gemm_bt<0><<<dim3(12, 128), 256, 0, stream>>>(hbuf, wq, qkv_b, qkvb,
                                                  nullptr, nullptr, 16384, 1536, 512);
    attn_kernel<<<dim3(8, 64), 512, 0, stream>>>(qkvb, attno);
    gemm_bt<2><<<dim3(4, 128), 256, 0, stream>>>(attno, wpj, proj_b, x1,
                                                 x, mod + 2 * 512, 16384, 512, 512);

    ln_mod_kernel<<<16384 / 4, 256, 0, stream>>>(x1, ln2_w, ln2_b, mod, 3 * 512, 4 * 512, hbuf);
    gemm_bt<1><<<dim3(16, 128), 256, 0, stream>>>(hbuf, w1, fc1_b, fc1g,
                                                  nullptr, nullptr, 16384, 2048, 512);
    gemm_bt<2><<<dim3(4, 128), 256, 0, stream>>>(fc1g, w2, fc2_b, (float*)d_out,
                                                 x1, mod + 5 * 512, 16384, 512, 2048);
}